// Round 1
// baseline (1202.041 us; speedup 1.0000x reference)
//
#include <hip/hip_runtime.h>
#include <hip/hip_bf16.h>
#include <stdint.h>

#define D 128

typedef unsigned int u32;
typedef unsigned short u16;
typedef __attribute__((ext_vector_type(8))) short short8;
typedef __attribute__((ext_vector_type(4))) float f32x4;

__device__ __forceinline__ float bf2f(u32 lo16) {
  return __uint_as_float(lo16 << 16);
}
__device__ __forceinline__ u16 f2bf(float f) {
  u32 u = __float_as_uint(f);
  u32 r = (u + 0x7FFFu + ((u >> 16) & 1u)) >> 16;
  return (u16)r;
}

// ---------------- converts ----------------
__global__ void k_f2b4(const float* __restrict__ in, u16* __restrict__ out, int n4) {
  int i = blockIdx.x * blockDim.x + threadIdx.x;
  if (i < n4) {
    float4 v = ((const float4*)in)[i];
    ushort4 o;
    o.x = f2bf(v.x); o.y = f2bf(v.y); o.z = f2bf(v.z); o.w = f2bf(v.w);
    ((ushort4*)out)[i] = o;
  }
}

// ---------------- CSR build ----------------
__global__ void k_count(const int* __restrict__ dst, int* __restrict__ cnt, int E) {
  int e = blockIdx.x * blockDim.x + threadIdx.x;
  if (e < E) atomicAdd(&cnt[dst[e]], 1);
}

__global__ void k_scan1(const int* __restrict__ cnt, int* __restrict__ rp,
                        int* __restrict__ bsum, int N) {
  __shared__ int sh[256];
  int tid = threadIdx.x;
  int i = blockIdx.x * 256 + tid;
  int v = (i < N) ? cnt[i] : 0;
  sh[tid] = v;
  __syncthreads();
  for (int o = 1; o < 256; o <<= 1) {
    int x = (tid >= o) ? sh[tid - o] : 0;
    __syncthreads();
    sh[tid] += x;
    __syncthreads();
  }
  if (i < N) rp[i] = sh[tid] - v;      // block-local exclusive
  if (tid == 255) bsum[blockIdx.x] = sh[255];
}

__global__ void k_scan2(int* __restrict__ bsum, int NB) {
  __shared__ int sh[512];
  int tid = threadIdx.x;
  int v = (tid < NB) ? bsum[tid] : 0;
  sh[tid] = v;
  __syncthreads();
  for (int o = 1; o < 512; o <<= 1) {
    int x = (tid >= o) ? sh[tid - o] : 0;
    __syncthreads();
    sh[tid] += x;
    __syncthreads();
  }
  if (tid < NB) bsum[tid] = sh[tid] - v;  // exclusive
}

__global__ void k_scan3(int* __restrict__ rp, const int* __restrict__ bsum, int N, int E) {
  int i = blockIdx.x * 256 + threadIdx.x;
  if (i < N) rp[i] += bsum[blockIdx.x];
  if (i == 0) rp[N] = E;
}

__global__ void k_scatter(const int* __restrict__ src, const int* __restrict__ dst,
                          const int* __restrict__ rp, int* __restrict__ fill,
                          int* __restrict__ csr, int E) {
  int e = blockIdx.x * blockDim.x + threadIdx.x;
  if (e < E) {
    int d2 = dst[e];
    int pos = rp[d2] + atomicAdd(&fill[d2], 1);
    csr[pos] = src[e];
  }
}

// ---------------- aggregation: out[n] = t(X[n]) + sum_{e: dst=n} t(X[src]) ----------------
// t(v) = relu? max(scale*v+shift,0) : scale*v+shift ; scale==null -> identity
__global__ __launch_bounds__(256)
void k_agg(const u16* __restrict__ X, const int* __restrict__ rp,
           const int* __restrict__ csr, const float* __restrict__ scale,
           const float* __restrict__ shift, int relu,
           u16* __restrict__ out, int N) {
  int node = blockIdx.x * 4 + (threadIdx.x >> 6);
  if (node >= N) return;
  int lane = threadIdx.x & 63;
  int c0 = lane * 2;
  float s0 = 1.f, s1 = 1.f, h0 = 0.f, h1 = 0.f;
  if (scale) { s0 = scale[c0]; s1 = scale[c0 + 1]; h0 = shift[c0]; h1 = shift[c0 + 1]; }
  u32 v = *(const u32*)(X + (size_t)node * D + c0);
  float a0 = bf2f(v & 0xFFFFu) * s0 + h0;
  float a1 = bf2f(v >> 16) * s1 + h1;
  if (relu) { a0 = fmaxf(a0, 0.f); a1 = fmaxf(a1, 0.f); }
  int b = rp[node], e = rp[node + 1];
  for (int i = b; i < e; ++i) {
    int s = csr[i];
    u32 w = *(const u32*)(X + (size_t)s * D + c0);
    float t0 = bf2f(w & 0xFFFFu) * s0 + h0;
    float t1 = bf2f(w >> 16) * s1 + h1;
    if (relu) { t0 = fmaxf(t0, 0.f); t1 = fmaxf(t1, 0.f); }
    a0 += t0; a1 += t1;
  }
  u32 o = (u32)f2bf(a0) | ((u32)f2bf(a1) << 16);
  *(u32*)(out + (size_t)node * D + c0) = o;
}

// ---------------- fused GEMM: C = t(A) @ W^T + bias, optional column stats ----------------
// A: N x 128 bf16, W: 128(out) x 128(in) bf16, C: N x 128 bf16
#define LDP 136
__global__ __launch_bounds__(256, 2)
void k_gemm(const u16* __restrict__ A, const u16* __restrict__ W,
            const float* __restrict__ bias, const float* __restrict__ scale,
            const float* __restrict__ shift, int relu,
            u16* __restrict__ Cc, float* __restrict__ stats, int do_stats, int N) {
  __shared__ u16 lsA[128 * LDP];
  __shared__ u16 lsW[128 * LDP];
  const int t = threadIdx.x;
  const int rowBase = blockIdx.x * 128;

#pragma unroll
  for (int i = 0; i < 8; ++i) {
    int chunk = i * 256 + t;      // 0..2047
    int r = chunk >> 4;           // 0..127
    int c = (chunk & 15) << 3;    // 0..120
    int gr = rowBase + r;
    uint4 v = make_uint4(0, 0, 0, 0);
    if (gr < N) v = *(const uint4*)(A + (size_t)gr * D + c);
    u32 vv[4] = {v.x, v.y, v.z, v.w};
    if (scale) {
#pragma unroll
      for (int j = 0; j < 4; ++j) {
        int cc = c + j * 2;
        float f0 = bf2f(vv[j] & 0xFFFFu) * scale[cc] + shift[cc];
        float f1 = bf2f(vv[j] >> 16) * scale[cc + 1] + shift[cc + 1];
        if (relu) { f0 = fmaxf(f0, 0.f); f1 = fmaxf(f1, 0.f); }
        vv[j] = (u32)f2bf(f0) | ((u32)f2bf(f1) << 16);
      }
    }
    *(uint4*)&lsA[r * LDP + c] = make_uint4(vv[0], vv[1], vv[2], vv[3]);
    *(uint4*)&lsW[r * LDP + c] = *(const uint4*)(W + r * D + c);
  }
  __syncthreads();

  const int wv = t >> 6;
  const int lane = t & 63;
  const int lrow = lane & 15;
  const int lk = (lane >> 4) << 3;

  f32x4 acc[2][8];
#pragma unroll
  for (int m = 0; m < 2; ++m)
#pragma unroll
    for (int n = 0; n < 8; ++n)
      acc[m][n] = (f32x4){0.f, 0.f, 0.f, 0.f};

#pragma unroll
  for (int kk = 0; kk < 128; kk += 32) {
    short8 af[2];
#pragma unroll
    for (int m = 0; m < 2; ++m)
      af[m] = *(const short8*)&lsA[(wv * 32 + m * 16 + lrow) * LDP + kk + lk];
#pragma unroll
    for (int n = 0; n < 8; ++n) {
      short8 bfv = *(const short8*)&lsW[(n * 16 + lrow) * LDP + kk + lk];
#pragma unroll
      for (int m = 0; m < 2; ++m)
        acc[m][n] = __builtin_amdgcn_mfma_f32_16x16x32_bf16(af[m], bfv, acc[m][n], 0, 0, 0);
    }
  }

  // epilogue: bias, store bf16, column stats
  const int rgrp = (lane >> 4) << 2;
  float sacc[8], qacc[8];
#pragma unroll
  for (int n = 0; n < 8; ++n) { sacc[n] = 0.f; qacc[n] = 0.f; }
#pragma unroll
  for (int m = 0; m < 2; ++m) {
    int rb = rowBase + wv * 32 + m * 16 + rgrp;
#pragma unroll
    for (int n = 0; n < 8; ++n) {
      int col = n * 16 + lrow;
      float bb = bias[col];
      f32x4 a = acc[m][n];
#pragma unroll
      for (int r = 0; r < 4; ++r) {
        int gr = rb + r;
        if (gr < N) {
          float vv = a[r] + bb;
          Cc[(size_t)gr * D + col] = f2bf(vv);
          sacc[n] += vv; qacc[n] += vv * vv;
        }
      }
    }
  }
  if (do_stats) {
#pragma unroll
    for (int n = 0; n < 8; ++n) {
      float s = sacc[n], q = qacc[n];
      s += __shfl_xor(s, 16, 64); q += __shfl_xor(q, 16, 64);
      s += __shfl_xor(s, 32, 64); q += __shfl_xor(q, 32, 64);
      if (lane < 16) {
        int col = n * 16 + lrow;
        atomicAdd(&stats[col], s);
        atomicAdd(&stats[D + col], q);
      }
    }
  }
}

// ---------------- BN finalize ----------------
__global__ void k_finalize(const float* __restrict__ stats, const float* __restrict__ g,
                           const float* __restrict__ be, float* __restrict__ scale,
                           float* __restrict__ shift, float invN) {
  int c = threadIdx.x;
  if (c < D) {
    float mean = stats[c] * invN;
    float var = stats[D + c] * invN - mean * mean;
    float rs = rsqrtf(var + 1e-5f);
    float sc = g[c] * rs;
    scale[c] = sc;
    shift[c] = be[c] - mean * sc;
  }
}

// ---------------- final: out = relu(bn(X))[mask] @ W_out^T + b_out ----------------
#define COUT 10
__global__ __launch_bounds__(256)
void k_out(const u16* __restrict__ X, const int* __restrict__ mask,
           const float* __restrict__ scale, const float* __restrict__ shift,
           const float* __restrict__ Wout, const float* __restrict__ bout,
           float* __restrict__ out, int M) {
  int w = blockIdx.x * 4 + (threadIdx.x >> 6);
  if (w >= M) return;
  int lane = threadIdx.x & 63;
  int c0 = lane * 2;
  int node = mask[w];
  u32 v = *(const u32*)(X + (size_t)node * D + c0);
  float a0 = fmaxf(bf2f(v & 0xFFFFu) * scale[c0] + shift[c0], 0.f);
  float a1 = fmaxf(bf2f(v >> 16) * scale[c0 + 1] + shift[c0 + 1], 0.f);
  float p[COUT];
#pragma unroll
  for (int c = 0; c < COUT; ++c) {
    float2 wv = *(const float2*)(Wout + c * D + c0);
    p[c] = a0 * wv.x + a1 * wv.y;
  }
#pragma unroll
  for (int c = 0; c < COUT; ++c) {
#pragma unroll
    for (int o = 32; o >= 1; o >>= 1)
      p[c] += __shfl_xor(p[c], o, 64);
  }
  if (lane == 0) {
#pragma unroll
    for (int c = 0; c < COUT; ++c)
      out[(size_t)w * COUT + c] = p[c] + bout[c];
  }
}

// ---------------- host ----------------
extern "C" void kernel_launch(void* const* d_in, const int* in_sizes, int n_in,
                              void* d_out, int out_size, void* d_ws, size_t ws_size,
                              hipStream_t stream) {
  const float* x      = (const float*)d_in[0];
  const int*   ei     = (const int*)d_in[1];
  const int*   mask   = (const int*)d_in[2];
  const float* W_init = (const float*)d_in[3];
  const float* b_init = (const float*)d_in[4];
  const float* W1s    = (const float*)d_in[5];
  const float* b1s    = (const float*)d_in[6];
  const float* g1s    = (const float*)d_in[7];
  const float* be1s   = (const float*)d_in[8];
  const float* W2s    = (const float*)d_in[9];
  const float* b2s    = (const float*)d_in[10];
  const float* g2s    = (const float*)d_in[11];
  const float* be2s   = (const float*)d_in[12];
  const float* W_out  = (const float*)d_in[13];
  const float* b_out  = (const float*)d_in[14];

  const int N = in_sizes[0] / D;
  const int E = in_sizes[1] / 2;
  const int M = in_sizes[2];
  const int L = in_sizes[6] / D;

  const int* srcp = ei;
  const int* dstp = ei + E;

  char* ws = (char*)d_ws;
  size_t off = 0;
  auto take = [&](size_t bytes) -> char* {
    off = (off + 255) & ~(size_t)255;
    char* p = ws + off;
    off += bytes;
    return p;
  };
  u16* B0    = (u16*)take((size_t)N * D * 2);
  u16* B1    = (u16*)take((size_t)N * D * 2);
  u16* B2    = (u16*)take((size_t)N * D * 2);
  u16* Wb    = (u16*)take((size_t)(1 + 2 * L) * D * D * 2);
  int* csr   = (int*)take((size_t)E * 4);
  int* rp    = (int*)take((size_t)(N + 1) * 4);
  int* cnt   = (int*)take((size_t)N * 4 * 2);
  int* fill  = cnt + N;
  int* bsum  = (int*)take(4096);
  float* stats  = (float*)take(1024);
  float* scaleP = (float*)take(512);
  float* shiftP = (float*)take(512);
  float* scaleQ = (float*)take(512);
  float* shiftQ = (float*)take(512);
  if (off > ws_size) return;  // insufficient workspace -> loud failure

  // zero counters
  hipMemsetAsync(cnt, 0, (size_t)N * 8, stream);

  // converts to bf16
  {
    int n4 = N * D / 4;
    k_f2b4<<<(n4 + 255) / 256, 256, 0, stream>>>(x, B0, n4);
    int w4 = D * D / 4;
    k_f2b4<<<(w4 + 255) / 256, 256, 0, stream>>>(W_init, Wb, w4);
    int w4L = L * D * D / 4;
    k_f2b4<<<(w4L + 255) / 256, 256, 0, stream>>>(W1s, Wb + (size_t)D * D, w4L);
    k_f2b4<<<(w4L + 255) / 256, 256, 0, stream>>>(W2s, Wb + (size_t)(1 + L) * D * D, w4L);
  }

  // CSR build
  int NB = (N + 255) / 256;
  k_count<<<(E + 255) / 256, 256, 0, stream>>>(dstp, cnt, E);
  k_scan1<<<NB, 256, 0, stream>>>(cnt, rp, bsum, N);
  k_scan2<<<1, 512, 0, stream>>>(bsum, NB);
  k_scan3<<<NB, 256, 0, stream>>>(rp, bsum, N, E);
  k_scatter<<<(E + 255) / 256, 256, 0, stream>>>(srcp, dstp, rp, fill, csr, E);

  // init linear: B1 = x @ W_init^T + b_init
  int GB = (N + 127) / 128;
  k_gemm<<<GB, 256, 0, stream>>>(B0, Wb, b_init, nullptr, nullptr, 0, B1, nullptr, 0, N);

  const float* aggScale = nullptr;
  const float* aggShift = nullptr;
  int aggRelu = 0;
  float invN = 1.0f / (float)N;

  for (int l = 0; l < L; ++l) {
    // h0 = t(X) + sum_nb t(X)
    k_agg<<<(N + 3) / 4, 256, 0, stream>>>(B1, rp, csr, aggScale, aggShift, aggRelu, B2, N);
    // h1 = h0 @ W1^T + b1  (+stats)
    hipMemsetAsync(stats, 0, 1024, stream);
    k_gemm<<<GB, 256, 0, stream>>>(B2, Wb + (size_t)(1 + l) * D * D, b1s + l * D,
                                   nullptr, nullptr, 0, B0, stats, 1, N);
    k_finalize<<<1, 128, 0, stream>>>(stats, g1s + l * D, be1s + l * D, scaleP, shiftP, invN);
    // h2 = relu(bn(h1)) @ W2^T + b2  (+stats)
    hipMemsetAsync(stats, 0, 1024, stream);
    k_gemm<<<GB, 256, 0, stream>>>(B0, Wb + (size_t)(1 + L + l) * D * D, b2s + l * D,
                                   scaleP, shiftP, 1, B1, stats, 1, N);
    k_finalize<<<1, 128, 0, stream>>>(stats, g2s + l * D, be2s + l * D, scaleQ, shiftQ, invN);
    aggScale = scaleQ; aggShift = shiftQ; aggRelu = 1;
  }

  // out = relu(bn(X))[mask] @ W_out^T + b_out
  k_out<<<(M + 3) / 4, 256, 0, stream>>>(B1, mask, scaleQ, shiftQ, W_out, b_out,
                                         (float*)d_out, M);
}

// Round 2
// 951.527 us; speedup vs baseline: 1.2633x; 1.2633x over previous
//
#include <hip/hip_runtime.h>
#include <hip/hip_bf16.h>
#include <stdint.h>

#define D 128

typedef unsigned int u32;
typedef unsigned short u16;
typedef __attribute__((ext_vector_type(8))) short short8;
typedef __attribute__((ext_vector_type(4))) float f32x4;

__device__ __forceinline__ float bf2f(u32 lo16) {
  return __uint_as_float(lo16 << 16);
}
__device__ __forceinline__ u16 f2bf(float f) {
  u32 u = __float_as_uint(f);
  u32 r = (u + 0x7FFFu + ((u >> 16) & 1u)) >> 16;
  return (u16)r;
}

// async global->LDS, 16B per lane; lds dest must be wave-uniform base (+lane*16)
__device__ __forceinline__ void gload16(const void* g, void* l) {
  __builtin_amdgcn_global_load_lds(
      (const __attribute__((address_space(1))) u32*)g,
      (__attribute__((address_space(3))) u32*)l, 16, 0, 0);
}

// swizzles (keep write/read pairs consistent)
#define ASWZ(r, b) ((b) ^ (((r)&7) << 4))                      // 128B rows (A/W stage)
#define CSWZ(r, b) ((b) ^ (((r)&7) << 4) ^ (((r)&8) << 1))     // 256B rows (C restage)

// ---------------- converts ----------------
__global__ void k_f2b4(const float* __restrict__ in, u16* __restrict__ out, int n4) {
  int i = blockIdx.x * blockDim.x + threadIdx.x;
  if (i < n4) {
    float4 v = ((const float4*)in)[i];
    ushort4 o;
    o.x = f2bf(v.x); o.y = f2bf(v.y); o.z = f2bf(v.z); o.w = f2bf(v.w);
    ((ushort4*)out)[i] = o;
  }
}

// ---------------- CSR build ----------------
__global__ void k_count(const int* __restrict__ dst, int* __restrict__ cnt, int E) {
  int e = blockIdx.x * blockDim.x + threadIdx.x;
  if (e < E) atomicAdd(&cnt[dst[e]], 1);
}

__global__ void k_scan1(const int* __restrict__ cnt, int* __restrict__ rp,
                        int* __restrict__ bsum, int N) {
  __shared__ int sh[256];
  int tid = threadIdx.x;
  int i = blockIdx.x * 256 + tid;
  int v = (i < N) ? cnt[i] : 0;
  sh[tid] = v;
  __syncthreads();
  for (int o = 1; o < 256; o <<= 1) {
    int x = (tid >= o) ? sh[tid - o] : 0;
    __syncthreads();
    sh[tid] += x;
    __syncthreads();
  }
  if (i < N) rp[i] = sh[tid] - v;
  if (tid == 255) bsum[blockIdx.x] = sh[255];
}

__global__ void k_scan2(int* __restrict__ bsum, int NB) {
  __shared__ int sh[512];
  int tid = threadIdx.x;
  int v = (tid < NB) ? bsum[tid] : 0;
  sh[tid] = v;
  __syncthreads();
  for (int o = 1; o < 512; o <<= 1) {
    int x = (tid >= o) ? sh[tid - o] : 0;
    __syncthreads();
    sh[tid] += x;
    __syncthreads();
  }
  if (tid < NB) bsum[tid] = sh[tid] - v;
}

__global__ void k_scan3(int* __restrict__ rp, const int* __restrict__ bsum, int N, int E) {
  int i = blockIdx.x * 256 + threadIdx.x;
  if (i < N) rp[i] += bsum[blockIdx.x];
  if (i == 0) rp[N] = E;
}

__global__ void k_scatter(const int* __restrict__ src, const int* __restrict__ dst,
                          const int* __restrict__ rp, int* __restrict__ fill,
                          int* __restrict__ csr, int E) {
  int e = blockIdx.x * blockDim.x + threadIdx.x;
  if (e < E) {
    int d2 = dst[e];
    int pos = rp[d2] + atomicAdd(&fill[d2], 1);
    csr[pos] = src[e];
  }
}

// ---------------- aggregation: out[n] = t(X[n]) + sum_{e: dst=n} t(X[src]) ----------------
__global__ __launch_bounds__(256)
void k_agg(const u16* __restrict__ X, const int* __restrict__ rp,
           const int* __restrict__ csr, const float* __restrict__ scale,
           const float* __restrict__ shift, int relu,
           u16* __restrict__ out, int N) {
  int node = blockIdx.x * 4 + (threadIdx.x >> 6);
  if (node >= N) return;
  int lane = threadIdx.x & 63;
  int c0 = lane * 2;
  float s0 = 1.f, s1 = 1.f, h0 = 0.f, h1 = 0.f;
  if (scale) { s0 = scale[c0]; s1 = scale[c0 + 1]; h0 = shift[c0]; h1 = shift[c0 + 1]; }
  u32 v = *(const u32*)(X + (size_t)node * D + c0);
  float a0 = bf2f(v & 0xFFFFu) * s0 + h0;
  float a1 = bf2f(v >> 16) * s1 + h1;
  if (relu) { a0 = fmaxf(a0, 0.f); a1 = fmaxf(a1, 0.f); }
  int b = rp[node], e = rp[node + 1];
  for (int i = b; i < e; ++i) {
    int s = csr[i];
    u32 w = *(const u32*)(X + (size_t)s * D + c0);
    float t0 = bf2f(w & 0xFFFFu) * s0 + h0;
    float t1 = bf2f(w >> 16) * s1 + h1;
    if (relu) { t0 = fmaxf(t0, 0.f); t1 = fmaxf(t1, 0.f); }
    a0 += t0; a1 += t1;
  }
  u32 o = (u32)f2bf(a0) | ((u32)f2bf(a1) << 16);
  *(u32*)(out + (size_t)node * D + c0) = o;
}

// ---------------- fused GEMM: C = t(A) @ W^T + bias; per-block BN partials ----------------
// A: N x 128 bf16, W: 128 x 128 bf16 (row-major, out x in), C: N x 128 bf16
// HAS_SCALE: A := relu(A*scale+shift) on load (reg-staged); else global_load_lds direct.
template <int HAS_SCALE>
__global__ __launch_bounds__(256, 4)
void k_gemm2(const u16* __restrict__ A, const u16* __restrict__ W,
             const float* __restrict__ bias, const float* __restrict__ scale,
             const float* __restrict__ shift,
             u16* __restrict__ Cc, float* __restrict__ partials, int do_stats, int N) {
  __shared__ u16 ls[128 * 128];      // phase1: A half [0,16K) + W half [16K,32K); phase2: C
  __shared__ float swave[4][256];
  u16* lsA = ls;
  u16* lsW = ls + 64 * 128;

  const int t = threadIdx.x;
  const int wv = t >> 6;
  const int lane = t & 63;
  const int rowBase = blockIdx.x * 128;
  const int lrow = lane & 15;
  const int lkb = (lane >> 4) << 4;  // fragment byte offset within 128B k-row

  f32x4 acc[2][8];
#pragma unroll
  for (int m = 0; m < 2; ++m)
#pragma unroll
    for (int n = 0; n < 8; ++n)
      acc[m][n] = (f32x4){0.f, 0.f, 0.f, 0.f};

#pragma unroll
  for (int h = 0; h < 2; ++h) {
    if (h) __syncthreads();  // all fragment reads of half 0 done before overwrite

    // ---- stage A half + W half ----
#pragma unroll
    for (int i = 0; i < 4; ++i) {
      int r0 = wv * 32 + i * 8;          // wave-uniform
      int r = r0 + (lane >> 3);          // 0..127
      int ch = lane & 7;                 // 16B chunk within 128B row
      int sxcol = (ch << 4) ^ ((r & 7) << 4);  // pre-swizzled source column
      // W: always async direct
      gload16((const char*)W + (size_t)r * 256 + h * 128 + sxcol,
              (char*)lsW + r0 * 128);
      if constexpr (!HAS_SCALE) {
        int gr = rowBase + r;
        if (gr >= N) gr = N - 1;  // clamp (dup row; stores/stats guarded later)
        gload16((const char*)A + (size_t)gr * 256 + h * 128 + sxcol,
                (char*)lsA + r0 * 128);
      } else {
        int gr = rowBase + r;
        uint4 v = make_uint4(0, 0, 0, 0);
        if (gr < N) v = *(const uint4*)(A + (size_t)gr * D + h * 64 + ch * 8);
        u32 vv[4] = {v.x, v.y, v.z, v.w};
        int kb = h * 64 + ch * 8;
#pragma unroll
        for (int j = 0; j < 4; ++j) {
          int k2 = kb + j * 2;
          float f0 = fmaxf(bf2f(vv[j] & 0xFFFFu) * scale[k2] + shift[k2], 0.f);
          float f1 = fmaxf(bf2f(vv[j] >> 16) * scale[k2 + 1] + shift[k2 + 1], 0.f);
          vv[j] = (u32)f2bf(f0) | ((u32)f2bf(f1) << 16);
        }
        u32 s = (u32)ASWZ(r, r * 128 + ch * 16);
        *(uint4*)((char*)lsA + s) = make_uint4(vv[0], vv[1], vv[2], vv[3]);
      }
    }
    __syncthreads();  // compiler drains vmcnt/lgkmcnt before s_barrier

    // ---- compute: K-half = 2 x K32 MFMA steps ----
#pragma unroll
    for (int kk2 = 0; kk2 < 2; ++kk2) {
      const int cb = kk2 * 64 + lkb;
      short8 af[2];
#pragma unroll
      for (int m = 0; m < 2; ++m) {
        int r = wv * 32 + m * 16 + lrow;
        af[m] = *(const short8*)((const char*)lsA + ASWZ(r, r * 128 + cb));
      }
#pragma unroll
      for (int n = 0; n < 8; ++n) {
        int rw = n * 16 + lrow;
        short8 bw = *(const short8*)((const char*)lsW + ASWZ(rw, rw * 128 + cb));
#pragma unroll
        for (int m = 0; m < 2; ++m)
          acc[m][n] = __builtin_amdgcn_mfma_f32_16x16x32_bf16(af[m], bw, acc[m][n], 0, 0, 0);
      }
    }
  }

  // ---- epilogue: restage C in LDS (reuse ls), block-local BN partials ----
  __syncthreads();  // all fragment reads done before ls is overwritten with C

  const int rgrp = (lane >> 4) << 2;
  float sacc[8], qacc[8];
#pragma unroll
  for (int n = 0; n < 8; ++n) { sacc[n] = 0.f; qacc[n] = 0.f; }

#pragma unroll
  for (int m = 0; m < 2; ++m) {
    int rl = wv * 32 + m * 16 + rgrp;
#pragma unroll
    for (int n = 0; n < 8; ++n) {
      int col = n * 16 + lrow;
      float bb = bias[col];
      f32x4 a = acc[m][n];
#pragma unroll
      for (int r = 0; r < 4; ++r) {
        int row = rl + r;
        float vv = a[r] + bb;
        *(u16*)((char*)ls + CSWZ(row, row * 256 + col * 2)) = f2bf(vv);
        if (rowBase + row < N) { sacc[n] += vv; qacc[n] += vv * vv; }
      }
    }
  }
  if (do_stats) {
#pragma unroll
    for (int n = 0; n < 8; ++n) {
      float s = sacc[n], q = qacc[n];
      s += __shfl_xor(s, 16, 64); q += __shfl_xor(q, 16, 64);
      s += __shfl_xor(s, 32, 64); q += __shfl_xor(q, 32, 64);
      if (lane < 16) {
        int col = n * 16 + lrow;
        swave[wv][col] = s;
        swave[wv][128 + col] = q;
      }
    }
  }
  __syncthreads();

  // coalesced C copy-out
#pragma unroll
  for (int i = 0; i < 8; ++i) {
    int chunk = i * 256 + t;
    u32 s = (u32)chunk << 4;
    int row = s >> 8;
    if (rowBase + row < N) {
      uint4 v = *(const uint4*)((const char*)ls + CSWZ(row, s));
      *(uint4*)((char*)Cc + (size_t)(rowBase + row) * 256 + (s & 255)) = v;
    }
  }
  if (do_stats) {
    float tot = swave[0][t & 255] + swave[1][t & 255] + swave[2][t & 255] + swave[3][t & 255];
    partials[(size_t)blockIdx.x * 256 + (t & 255)] = tot;
  }
}

// ---------------- BN partials reduce + finalize ----------------
__global__ __launch_bounds__(1024)
void k_redfin(const float* __restrict__ partials, int NB, const float* __restrict__ g,
              const float* __restrict__ be, float* __restrict__ scale,
              float* __restrict__ shift, float invN) {
  __shared__ float sh[4][256];
  __shared__ float tot[256];
  int t = threadIdx.x;
  int col = t & 255, slice = t >> 8;
  float s = 0.f;
  for (int b = slice; b < NB; b += 4) s += partials[(size_t)b * 256 + col];
  sh[slice][col] = s;
  __syncthreads();
  if (slice == 0) tot[col] = sh[0][col] + sh[1][col] + sh[2][col] + sh[3][col];
  __syncthreads();
  if (t < 128) {
    float mean = tot[t] * invN;
    float var = tot[128 + t] * invN - mean * mean;
    float rs = rsqrtf(var + 1e-5f);
    float sc = g[t] * rs;
    scale[t] = sc;
    shift[t] = be[t] - mean * sc;
  }
}

// ---------------- final: out = relu(bn(X))[mask] @ W_out^T + b_out ----------------
#define COUT 10
__global__ __launch_bounds__(256)
void k_out(const u16* __restrict__ X, const int* __restrict__ mask,
           const float* __restrict__ scale, const float* __restrict__ shift,
           const float* __restrict__ Wout, const float* __restrict__ bout,
           float* __restrict__ out, int M) {
  int w = blockIdx.x * 4 + (threadIdx.x >> 6);
  if (w >= M) return;
  int lane = threadIdx.x & 63;
  int c0 = lane * 2;
  int node = mask[w];
  u32 v = *(const u32*)(X + (size_t)node * D + c0);
  float a0 = fmaxf(bf2f(v & 0xFFFFu) * scale[c0] + shift[c0], 0.f);
  float a1 = fmaxf(bf2f(v >> 16) * scale[c0 + 1] + shift[c0 + 1], 0.f);
  float p[COUT];
#pragma unroll
  for (int c = 0; c < COUT; ++c) {
    float2 wv = *(const float2*)(Wout + c * D + c0);
    p[c] = a0 * wv.x + a1 * wv.y;
  }
#pragma unroll
  for (int c = 0; c < COUT; ++c) {
#pragma unroll
    for (int o = 32; o >= 1; o >>= 1)
      p[c] += __shfl_xor(p[c], o, 64);
  }
  if (lane == 0) {
#pragma unroll
    for (int c = 0; c < COUT; ++c)
      out[(size_t)w * COUT + c] = p[c] + bout[c];
  }
}

// ---------------- host ----------------
extern "C" void kernel_launch(void* const* d_in, const int* in_sizes, int n_in,
                              void* d_out, int out_size, void* d_ws, size_t ws_size,
                              hipStream_t stream) {
  const float* x      = (const float*)d_in[0];
  const int*   ei     = (const int*)d_in[1];
  const int*   mask   = (const int*)d_in[2];
  const float* W_init = (const float*)d_in[3];
  const float* b_init = (const float*)d_in[4];
  const float* W1s    = (const float*)d_in[5];
  const float* b1s    = (const float*)d_in[6];
  const float* g1s    = (const float*)d_in[7];
  const float* be1s   = (const float*)d_in[8];
  const float* W2s    = (const float*)d_in[9];
  const float* b2s    = (const float*)d_in[10];
  const float* g2s    = (const float*)d_in[11];
  const float* be2s   = (const float*)d_in[12];
  const float* W_out  = (const float*)d_in[13];
  const float* b_out  = (const float*)d_in[14];

  const int N = in_sizes[0] / D;
  const int E = in_sizes[1] / 2;
  const int M = in_sizes[2];
  const int L = in_sizes[6] / D;

  const int* srcp = ei;
  const int* dstp = ei + E;

  char* ws = (char*)d_ws;
  size_t off = 0;
  auto take = [&](size_t bytes) -> char* {
    off = (off + 255) & ~(size_t)255;
    char* p = ws + off;
    off += bytes;
    return p;
  };
  const int GB = (N + 127) / 128;
  u16* B0    = (u16*)take((size_t)N * D * 2);
  u16* B1    = (u16*)take((size_t)N * D * 2);
  u16* B2    = (u16*)take((size_t)N * D * 2);
  u16* Wb    = (u16*)take((size_t)(1 + 2 * L) * D * D * 2);
  int* csr   = (int*)take((size_t)E * 4);
  int* rp    = (int*)take((size_t)(N + 1) * 4);
  int* cnt   = (int*)take((size_t)N * 4 * 2);
  int* fill  = cnt + N;
  int* bsum  = (int*)take(4096);
  float* partials = (float*)take((size_t)GB * 256 * 4);
  float* scaleP = (float*)take(512);
  float* shiftP = (float*)take(512);
  float* scaleQ = (float*)take(512);
  float* shiftQ = (float*)take(512);
  if (off > ws_size) return;

  hipMemsetAsync(cnt, 0, (size_t)N * 8, stream);

  // converts to bf16
  {
    int n4 = N * D / 4;
    k_f2b4<<<(n4 + 255) / 256, 256, 0, stream>>>(x, B0, n4);
    int w4 = D * D / 4;
    k_f2b4<<<(w4 + 255) / 256, 256, 0, stream>>>(W_init, Wb, w4);
    int w4L = L * D * D / 4;
    k_f2b4<<<(w4L + 255) / 256, 256, 0, stream>>>(W1s, Wb + (size_t)D * D, w4L);
    k_f2b4<<<(w4L + 255) / 256, 256, 0, stream>>>(W2s, Wb + (size_t)(1 + L) * D * D, w4L);
  }

  // CSR build
  int NB = (N + 255) / 256;
  k_count<<<(E + 255) / 256, 256, 0, stream>>>(dstp, cnt, E);
  k_scan1<<<NB, 256, 0, stream>>>(cnt, rp, bsum, N);
  k_scan2<<<1, 512, 0, stream>>>(bsum, NB);
  k_scan3<<<NB, 256, 0, stream>>>(rp, bsum, N, E);
  k_scatter<<<(E + 255) / 256, 256, 0, stream>>>(srcp, dstp, rp, fill, csr, E);

  // init linear: B1 = x @ W_init^T + b_init
  k_gemm2<0><<<GB, 256, 0, stream>>>(B0, Wb, b_init, nullptr, nullptr, B1, partials, 0, N);

  const float* aggScale = nullptr;
  const float* aggShift = nullptr;
  int aggRelu = 0;
  float invN = 1.0f / (float)N;

  for (int l = 0; l < L; ++l) {
    k_agg<<<(N + 3) / 4, 256, 0, stream>>>(B1, rp, csr, aggScale, aggShift, aggRelu, B2, N);
    k_gemm2<0><<<GB, 256, 0, stream>>>(B2, Wb + (size_t)(1 + l) * D * D, b1s + l * D,
                                       nullptr, nullptr, B0, partials, 1, N);
    k_redfin<<<1, 1024, 0, stream>>>(partials, GB, g1s + l * D, be1s + l * D,
                                     scaleP, shiftP, invN);
    k_gemm2<1><<<GB, 256, 0, stream>>>(B0, Wb + (size_t)(1 + L + l) * D * D, b2s + l * D,
                                       scaleP, shiftP, B1, partials, 1, N);
    k_redfin<<<1, 1024, 0, stream>>>(partials, GB, g2s + l * D, be2s + l * D,
                                     scaleQ, shiftQ, invN);
    aggScale = scaleQ; aggShift = shiftQ; aggRelu = 1;
  }

  k_out<<<(M + 3) / 4, 256, 0, stream>>>(B1, mask, scaleQ, shiftQ, W_out, b_out,
                                         (float*)d_out, M);
}

// Round 3
// 824.705 us; speedup vs baseline: 1.4575x; 1.1538x over previous
//
#include <hip/hip_runtime.h>
#include <hip/hip_bf16.h>
#include <stdint.h>

#define D 128

typedef unsigned int u32;
typedef unsigned short u16;
typedef __attribute__((ext_vector_type(8))) short short8;
typedef __attribute__((ext_vector_type(4))) float f32x4;

__device__ __forceinline__ float bf2f(u32 lo16) {
  return __uint_as_float(lo16 << 16);
}
__device__ __forceinline__ u16 f2bf(float f) {
  u32 u = __float_as_uint(f);
  u32 r = (u + 0x7FFFu + ((u >> 16) & 1u)) >> 16;
  return (u16)r;
}
__device__ __forceinline__ u32 pack2(float a, float b) {
  return (u32)f2bf(a) | ((u32)f2bf(b) << 16);
}

// async global->LDS, 16B per lane; lds dest must be wave-uniform base (+lane*16)
__device__ __forceinline__ void gload16(const void* g, void* l) {
  __builtin_amdgcn_global_load_lds(
      (const __attribute__((address_space(1))) u32*)g,
      (__attribute__((address_space(3))) u32*)l, 16, 0, 0);
}

// swizzles (keep write/read pairs consistent)
#define ASWZ(r, b) ((b) ^ (((r)&7) << 4))                      // 128B rows (A/W stage)
#define CSWZ(r, b) ((b) ^ (((r)&7) << 4) ^ (((r)&8) << 1))     // 256B rows (C restage)

// ---------------- converts (weights only) ----------------
__global__ void k_f2b4(const float* __restrict__ in, u16* __restrict__ out, int n4) {
  int i = blockIdx.x * blockDim.x + threadIdx.x;
  if (i < n4) {
    float4 v = ((const float4*)in)[i];
    ushort4 o;
    o.x = f2bf(v.x); o.y = f2bf(v.y); o.z = f2bf(v.z); o.w = f2bf(v.w);
    ((ushort4*)out)[i] = o;
  }
}

// ---------------- CSR build ----------------
__global__ void k_count(const int* __restrict__ dst, int* __restrict__ cnt, int E) {
  int e = blockIdx.x * blockDim.x + threadIdx.x;
  if (e < E) atomicAdd(&cnt[dst[e]], 1);
}

__global__ void k_scan1(const int* __restrict__ cnt, int* __restrict__ rp,
                        int* __restrict__ bsum, int N) {
  __shared__ int sh[256];
  int tid = threadIdx.x;
  int i = blockIdx.x * 256 + tid;
  int v = (i < N) ? cnt[i] : 0;
  sh[tid] = v;
  __syncthreads();
  for (int o = 1; o < 256; o <<= 1) {
    int x = (tid >= o) ? sh[tid - o] : 0;
    __syncthreads();
    sh[tid] += x;
    __syncthreads();
  }
  if (i < N) rp[i] = sh[tid] - v;
  if (tid == 255) bsum[blockIdx.x] = sh[255];
}

__global__ void k_scan2(int* __restrict__ bsum, int NB) {
  __shared__ int sh[512];
  int tid = threadIdx.x;
  int v = (tid < NB) ? bsum[tid] : 0;
  sh[tid] = v;
  __syncthreads();
  for (int o = 1; o < 512; o <<= 1) {
    int x = (tid >= o) ? sh[tid - o] : 0;
    __syncthreads();
    sh[tid] += x;
    __syncthreads();
  }
  if (tid < NB) bsum[tid] = sh[tid] - v;
}

__global__ void k_scan3(int* __restrict__ rp, const int* __restrict__ bsum, int N, int E) {
  int i = blockIdx.x * 256 + threadIdx.x;
  if (i < N) rp[i] += bsum[blockIdx.x];
  if (i == 0) rp[N] = E;
}

__global__ void k_scatter(const int* __restrict__ src, const int* __restrict__ dst,
                          const int* __restrict__ rp, int* __restrict__ fill,
                          int* __restrict__ csr, int E) {
  int e = blockIdx.x * blockDim.x + threadIdx.x;
  if (e < E) {
    int d2 = dst[e];
    int pos = rp[d2] + atomicAdd(&fill[d2], 1);
    csr[pos] = src[e];
  }
}

// ---------------- aggregation v2: 4 edges in flight per wave ----------------
// out[n] = t(X[n]) + sum_{e: dst=n} t(X[src]); t = TR ? relu(x*scale+shift) : x
template <int TR>
__global__ __launch_bounds__(256)
void k_agg2(const u16* __restrict__ X, const int* __restrict__ rp,
            const int* __restrict__ csr, const float* __restrict__ scale,
            const float* __restrict__ shift,
            u16* __restrict__ out, int N) {
  int node = blockIdx.x * 4 + (threadIdx.x >> 6);
  if (node >= N) return;
  const int lane = threadIdx.x & 63;
  const int g = lane >> 4;    // edge-slot 0..3
  const int li = lane & 15;   // 16B chunk within row
  const int cb = li * 8;      // col base (8 bf16 per lane)

  float s[8], h[8];
  if constexpr (TR) {
#pragma unroll
    for (int j = 0; j < 8; j += 4) {
      *(float4*)&s[j] = *(const float4*)(scale + cb + j);
      *(float4*)&h[j] = *(const float4*)(shift + cb + j);
    }
  }
  float acc[8];
#pragma unroll
  for (int j = 0; j < 8; ++j) acc[j] = 0.f;

  const int b = rp[node];
  const int cnt = rp[node + 1] - b + 1;  // +1: item 0 = self row
  for (int it = g; it < cnt; it += 4) {
    int sidx = it ? csr[b + it - 1] : node;
    const uint4 v = *(const uint4*)(X + (size_t)sidx * D + cb);
    u32 w[4] = {v.x, v.y, v.z, v.w};
#pragma unroll
    for (int j = 0; j < 4; ++j) {
      float f0 = bf2f(w[j] & 0xFFFFu);
      float f1 = bf2f(w[j] >> 16);
      if constexpr (TR) {
        f0 = fmaxf(f0 * s[2 * j] + h[2 * j], 0.f);
        f1 = fmaxf(f1 * s[2 * j + 1] + h[2 * j + 1], 0.f);
      }
      acc[2 * j] += f0;
      acc[2 * j + 1] += f1;
    }
  }
  // combine the 4 edge-slots (butterfly over lane bits 4,5)
#pragma unroll
  for (int j = 0; j < 8; ++j) {
    acc[j] += __shfl_xor(acc[j], 16, 64);
    acc[j] += __shfl_xor(acc[j], 32, 64);
  }
  if (g == 0) {
    uint4 o;
    o.x = pack2(acc[0], acc[1]);
    o.y = pack2(acc[2], acc[3]);
    o.z = pack2(acc[4], acc[5]);
    o.w = pack2(acc[6], acc[7]);
    *(uint4*)(out + (size_t)node * D + cb) = o;
  }
}

// ---------------- fused GEMM: C = t(A) @ W^T + bias; per-block BN partials ----------------
// MODE 0: A bf16, global_load_lds direct
// MODE 1: A bf16, relu(A*scale+shift) on load (reg-staged)
// MODE 2: A fp32, convert on load (reg-staged)
template <int MODE>
__global__ __launch_bounds__(256, 4)
void k_gemm2(const u16* __restrict__ A, const u16* __restrict__ W,
             const float* __restrict__ bias, const float* __restrict__ scale,
             const float* __restrict__ shift,
             u16* __restrict__ Cc, float* __restrict__ partials, int do_stats, int N) {
  __shared__ u16 ls[128 * 128];      // phase1: A half [0,16K) + W half [16K,32K); phase2: C
  __shared__ float swave[4][256];
  u16* lsA = ls;
  u16* lsW = ls + 64 * 128;

  const int t = threadIdx.x;
  const int wv = t >> 6;
  const int lane = t & 63;
  const int rowBase = blockIdx.x * 128;
  const int lrow = lane & 15;
  const int lkb = (lane >> 4) << 4;  // fragment byte offset within 128B k-row

  f32x4 acc[2][8];
#pragma unroll
  for (int m = 0; m < 2; ++m)
#pragma unroll
    for (int n = 0; n < 8; ++n)
      acc[m][n] = (f32x4){0.f, 0.f, 0.f, 0.f};

#pragma unroll
  for (int h = 0; h < 2; ++h) {
    if (h) __syncthreads();  // all fragment reads of half 0 done before overwrite

    // ---- stage A half + W half ----
#pragma unroll
    for (int i = 0; i < 4; ++i) {
      int r0 = wv * 32 + i * 8;          // wave-uniform
      int r = r0 + (lane >> 3);          // 0..127
      int ch = lane & 7;                 // 16B chunk within 128B row
      int sxcol = (ch << 4) ^ ((r & 7) << 4);  // pre-swizzled source column
      // W: always async direct
      gload16((const char*)W + (size_t)r * 256 + h * 128 + sxcol,
              (char*)lsW + r0 * 128);
      if constexpr (MODE == 0) {
        int gr = rowBase + r;
        if (gr >= N) gr = N - 1;  // clamp (dup row; stores/stats guarded later)
        gload16((const char*)A + (size_t)gr * 256 + h * 128 + sxcol,
                (char*)lsA + r0 * 128);
      } else if constexpr (MODE == 1) {
        int gr = rowBase + r;
        uint4 v = make_uint4(0, 0, 0, 0);
        if (gr < N) v = *(const uint4*)(A + (size_t)gr * D + h * 64 + ch * 8);
        u32 vv[4] = {v.x, v.y, v.z, v.w};
        int kb = h * 64 + ch * 8;
#pragma unroll
        for (int j = 0; j < 4; ++j) {
          int k2 = kb + j * 2;
          float f0 = fmaxf(bf2f(vv[j] & 0xFFFFu) * scale[k2] + shift[k2], 0.f);
          float f1 = fmaxf(bf2f(vv[j] >> 16) * scale[k2 + 1] + shift[k2 + 1], 0.f);
          vv[j] = pack2(f0, f1);
        }
        u32 sz = (u32)ASWZ(r, r * 128 + ch * 16);
        *(uint4*)((char*)lsA + sz) = make_uint4(vv[0], vv[1], vv[2], vv[3]);
      } else {
        const float* Af = (const float*)A;
        int gr = rowBase + r;
        float4 v0 = make_float4(0.f, 0.f, 0.f, 0.f), v1 = v0;
        if (gr < N) {
          v0 = *(const float4*)(Af + (size_t)gr * D + h * 64 + ch * 8);
          v1 = *(const float4*)(Af + (size_t)gr * D + h * 64 + ch * 8 + 4);
        }
        u32 vv[4] = {pack2(v0.x, v0.y), pack2(v0.z, v0.w),
                     pack2(v1.x, v1.y), pack2(v1.z, v1.w)};
        u32 sz = (u32)ASWZ(r, r * 128 + ch * 16);
        *(uint4*)((char*)lsA + sz) = make_uint4(vv[0], vv[1], vv[2], vv[3]);
      }
    }
    __syncthreads();  // compiler drains vmcnt/lgkmcnt before s_barrier

    // ---- compute: K-half = 2 x K32 MFMA steps ----
#pragma unroll
    for (int kk2 = 0; kk2 < 2; ++kk2) {
      const int cb = kk2 * 64 + lkb;
      short8 af[2];
#pragma unroll
      for (int m = 0; m < 2; ++m) {
        int r = wv * 32 + m * 16 + lrow;
        af[m] = *(const short8*)((const char*)lsA + ASWZ(r, r * 128 + cb));
      }
#pragma unroll
      for (int n = 0; n < 8; ++n) {
        int rw = n * 16 + lrow;
        short8 bw = *(const short8*)((const char*)lsW + ASWZ(rw, rw * 128 + cb));
#pragma unroll
        for (int m = 0; m < 2; ++m)
          acc[m][n] = __builtin_amdgcn_mfma_f32_16x16x32_bf16(af[m], bw, acc[m][n], 0, 0, 0);
      }
    }
  }

  // ---- epilogue: restage C in LDS (reuse ls), block-local BN partials ----
  __syncthreads();  // all fragment reads done before ls is overwritten with C

  const int rgrp = (lane >> 4) << 2;
  float sacc[8], qacc[8];
#pragma unroll
  for (int n = 0; n < 8; ++n) { sacc[n] = 0.f; qacc[n] = 0.f; }

#pragma unroll
  for (int m = 0; m < 2; ++m) {
    int rl = wv * 32 + m * 16 + rgrp;
#pragma unroll
    for (int n = 0; n < 8; ++n) {
      int col = n * 16 + lrow;
      float bb = bias[col];
      f32x4 a = acc[m][n];
#pragma unroll
      for (int r = 0; r < 4; ++r) {
        int row = rl + r;
        float vv = a[r] + bb;
        *(u16*)((char*)ls + CSWZ(row, row * 256 + col * 2)) = f2bf(vv);
        if (rowBase + row < N) { sacc[n] += vv; qacc[n] += vv * vv; }
      }
    }
  }
  if (do_stats) {
#pragma unroll
    for (int n = 0; n < 8; ++n) {
      float s = sacc[n], q = qacc[n];
      s += __shfl_xor(s, 16, 64); q += __shfl_xor(q, 16, 64);
      s += __shfl_xor(s, 32, 64); q += __shfl_xor(q, 32, 64);
      if (lane < 16) {
        int col = n * 16 + lrow;
        swave[wv][col] = s;
        swave[wv][128 + col] = q;
      }
    }
  }
  __syncthreads();

  // coalesced C copy-out
#pragma unroll
  for (int i = 0; i < 8; ++i) {
    int chunk = i * 256 + t;
    u32 s = (u32)chunk << 4;
    int row = s >> 8;
    if (rowBase + row < N) {
      uint4 v = *(const uint4*)((const char*)ls + CSWZ(row, s));
      *(uint4*)((char*)Cc + (size_t)(rowBase + row) * 256 + (s & 255)) = v;
    }
  }
  if (do_stats) {
    float tot = swave[0][t & 255] + swave[1][t & 255] + swave[2][t & 255] + swave[3][t & 255];
    partials[(size_t)blockIdx.x * 256 + (t & 255)] = tot;
  }
}

// ---------------- BN partials reduce + finalize ----------------
__global__ __launch_bounds__(1024)
void k_redfin(const float* __restrict__ partials, int NB, const float* __restrict__ g,
              const float* __restrict__ be, float* __restrict__ scale,
              float* __restrict__ shift, float invN) {
  __shared__ float sh[4][256];
  __shared__ float tot[256];
  int t = threadIdx.x;
  int col = t & 255, slice = t >> 8;
  float s = 0.f;
  for (int b = slice; b < NB; b += 4) s += partials[(size_t)b * 256 + col];
  sh[slice][col] = s;
  __syncthreads();
  if (slice == 0) tot[col] = sh[0][col] + sh[1][col] + sh[2][col] + sh[3][col];
  __syncthreads();
  if (t < 128) {
    float mean = tot[t] * invN;
    float var = tot[128 + t] * invN - mean * mean;
    float rs = rsqrtf(var + 1e-5f);
    float sc = g[t] * rs;
    scale[t] = sc;
    shift[t] = be[t] - mean * sc;
  }
}

// ---------------- final: out = relu(bn(X))[mask] @ W_out^T + b_out ----------------
#define COUT 10
__global__ __launch_bounds__(256)
void k_out(const u16* __restrict__ X, const int* __restrict__ mask,
           const float* __restrict__ scale, const float* __restrict__ shift,
           const float* __restrict__ Wout, const float* __restrict__ bout,
           float* __restrict__ out, int M) {
  int w = blockIdx.x * 4 + (threadIdx.x >> 6);
  if (w >= M) return;
  int lane = threadIdx.x & 63;
  int c0 = lane * 2;
  int node = mask[w];
  u32 v = *(const u32*)(X + (size_t)node * D + c0);
  float a0 = fmaxf(bf2f(v & 0xFFFFu) * scale[c0] + shift[c0], 0.f);
  float a1 = fmaxf(bf2f(v >> 16) * scale[c0 + 1] + shift[c0 + 1], 0.f);
  float p[COUT];
#pragma unroll
  for (int c = 0; c < COUT; ++c) {
    float2 wv = *(const float2*)(Wout + c * D + c0);
    p[c] = a0 * wv.x + a1 * wv.y;
  }
#pragma unroll
  for (int c = 0; c < COUT; ++c) {
#pragma unroll
    for (int o = 32; o >= 1; o >>= 1)
      p[c] += __shfl_xor(p[c], o, 64);
  }
  if (lane == 0) {
#pragma unroll
    for (int c = 0; c < COUT; ++c)
      out[(size_t)w * COUT + c] = p[c] + bout[c];
  }
}

// ---------------- host ----------------
extern "C" void kernel_launch(void* const* d_in, const int* in_sizes, int n_in,
                              void* d_out, int out_size, void* d_ws, size_t ws_size,
                              hipStream_t stream) {
  const float* x      = (const float*)d_in[0];
  const int*   ei     = (const int*)d_in[1];
  const int*   mask   = (const int*)d_in[2];
  const float* W_init = (const float*)d_in[3];
  const float* b_init = (const float*)d_in[4];
  const float* W1s    = (const float*)d_in[5];
  const float* b1s    = (const float*)d_in[6];
  const float* g1s    = (const float*)d_in[7];
  const float* be1s   = (const float*)d_in[8];
  const float* W2s    = (const float*)d_in[9];
  const float* b2s    = (const float*)d_in[10];
  const float* g2s    = (const float*)d_in[11];
  const float* be2s   = (const float*)d_in[12];
  const float* W_out  = (const float*)d_in[13];
  const float* b_out  = (const float*)d_in[14];

  const int N = in_sizes[0] / D;
  const int E = in_sizes[1] / 2;
  const int M = in_sizes[2];
  const int L = in_sizes[6] / D;

  const int* srcp = ei;
  const int* dstp = ei + E;

  char* ws = (char*)d_ws;
  size_t off = 0;
  auto take = [&](size_t bytes) -> char* {
    off = (off + 255) & ~(size_t)255;
    char* p = ws + off;
    off += bytes;
    return p;
  };
  const int GB = (N + 127) / 128;
  u16* B0    = (u16*)take((size_t)N * D * 2);
  u16* B1    = (u16*)take((size_t)N * D * 2);
  u16* B2    = (u16*)take((size_t)N * D * 2);
  u16* Wb    = (u16*)take((size_t)(1 + 2 * L) * D * D * 2);
  int* csr   = (int*)take((size_t)E * 4);
  int* rp    = (int*)take((size_t)(N + 1) * 4);
  int* cnt   = (int*)take((size_t)N * 4 * 2);
  int* fill  = cnt + N;
  int* bsum  = (int*)take(4096);
  float* partials = (float*)take((size_t)GB * 256 * 4);
  float* scaleP = (float*)take(512);
  float* shiftP = (float*)take(512);
  float* scaleQ = (float*)take(512);
  float* shiftQ = (float*)take(512);
  if (off > ws_size) return;

  hipMemsetAsync(cnt, 0, (size_t)N * 8, stream);

  // weight converts to bf16
  {
    int w4 = D * D / 4;
    k_f2b4<<<(w4 + 255) / 256, 256, 0, stream>>>(W_init, Wb, w4);
    int w4L = L * D * D / 4;
    k_f2b4<<<(w4L + 255) / 256, 256, 0, stream>>>(W1s, Wb + (size_t)D * D, w4L);
    k_f2b4<<<(w4L + 255) / 256, 256, 0, stream>>>(W2s, Wb + (size_t)(1 + L) * D * D, w4L);
  }

  // CSR build
  int NB = (N + 255) / 256;
  k_count<<<(E + 255) / 256, 256, 0, stream>>>(dstp, cnt, E);
  k_scan1<<<NB, 256, 0, stream>>>(cnt, rp, bsum, N);
  k_scan2<<<1, 512, 0, stream>>>(bsum, NB);
  k_scan3<<<NB, 256, 0, stream>>>(rp, bsum, N, E);
  k_scatter<<<(E + 255) / 256, 256, 0, stream>>>(srcp, dstp, rp, fill, csr, E);

  // init linear: B1 = x @ W_init^T + b_init (fp32 A converted on load)
  k_gemm2<2><<<GB, 256, 0, stream>>>((const u16*)x, Wb, b_init, nullptr, nullptr,
                                     B1, partials, 0, N);

  float invN = 1.0f / (float)N;
  int AGB = (N + 3) / 4;

  for (int l = 0; l < L; ++l) {
    if (l == 0)
      k_agg2<0><<<AGB, 256, 0, stream>>>(B1, rp, csr, nullptr, nullptr, B2, N);
    else
      k_agg2<1><<<AGB, 256, 0, stream>>>(B1, rp, csr, scaleQ, shiftQ, B2, N);
    k_gemm2<0><<<GB, 256, 0, stream>>>(B2, Wb + (size_t)(1 + l) * D * D, b1s + l * D,
                                       nullptr, nullptr, B0, partials, 1, N);
    k_redfin<<<1, 1024, 0, stream>>>(partials, GB, g1s + l * D, be1s + l * D,
                                     scaleP, shiftP, invN);
    k_gemm2<1><<<GB, 256, 0, stream>>>(B0, Wb + (size_t)(1 + L + l) * D * D, b2s + l * D,
                                       scaleP, shiftP, B1, partials, 1, N);
    k_redfin<<<1, 1024, 0, stream>>>(partials, GB, g2s + l * D, be2s + l * D,
                                     scaleQ, shiftQ, invN);
  }

  k_out<<<(M + 3) / 4, 256, 0, stream>>>(B1, mask, scaleQ, shiftQ, W_out, b_out,
                                         (float*)d_out, M);
}

// Round 4
// 568.990 us; speedup vs baseline: 2.1126x; 1.4494x over previous
//
#include <hip/hip_runtime.h>
#include <hip/hip_bf16.h>
#include <stdint.h>

#define D 128

typedef unsigned int u32;
typedef unsigned short u16;
typedef __attribute__((ext_vector_type(8))) short short8;
typedef __attribute__((ext_vector_type(4))) float f32x4;

__device__ __forceinline__ float bf2f(u32 lo16) {
  return __uint_as_float(lo16 << 16);
}
__device__ __forceinline__ u16 f2bf(float f) {
  u32 u = __float_as_uint(f);
  u32 r = (u + 0x7FFFu + ((u >> 16) & 1u)) >> 16;
  return (u16)r;
}
__device__ __forceinline__ u32 pack2(float a, float b) {
  return (u32)f2bf(a) | ((u32)f2bf(b) << 16);
}

// async global->LDS, 16B per lane; lds dest must be wave-uniform base (+lane*16)
__device__ __forceinline__ void gload16(const void* g, void* l) {
  __builtin_amdgcn_global_load_lds(
      (const __attribute__((address_space(1))) u32*)g,
      (__attribute__((address_space(3))) u32*)l, 16, 0, 0);
}

// swizzles (keep write/read pairs consistent)
#define ASWZ(r, b) ((b) ^ (((r)&7) << 4))                      // 128B rows (A/W stage)
#define CSWZ(r, b) ((b) ^ (((r)&7) << 4) ^ (((r)&8) << 1))     // 256B rows (C restage)

// ---------------- converts (weights only) ----------------
__global__ void k_f2b4(const float* __restrict__ in, u16* __restrict__ out, int n4) {
  int i = blockIdx.x * blockDim.x + threadIdx.x;
  if (i < n4) {
    float4 v = ((const float4*)in)[i];
    ushort4 o;
    o.x = f2bf(v.x); o.y = f2bf(v.y); o.z = f2bf(v.z); o.w = f2bf(v.w);
    ((ushort4*)out)[i] = o;
  }
}

// ---------------- CSR build ----------------
__global__ void k_count(const int* __restrict__ dst, int* __restrict__ cnt, int E) {
  int e = blockIdx.x * blockDim.x + threadIdx.x;
  if (e < E) atomicAdd(&cnt[dst[e]], 1);
}

__global__ void k_scan1(const int* __restrict__ cnt, int* __restrict__ rp,
                        int* __restrict__ bsum, int N) {
  __shared__ int sh[256];
  int tid = threadIdx.x;
  int i = blockIdx.x * 256 + tid;
  int v = (i < N) ? cnt[i] : 0;
  sh[tid] = v;
  __syncthreads();
  for (int o = 1; o < 256; o <<= 1) {
    int x = (tid >= o) ? sh[tid - o] : 0;
    __syncthreads();
    sh[tid] += x;
    __syncthreads();
  }
  if (i < N) rp[i] = sh[tid] - v;
  if (tid == 255) bsum[blockIdx.x] = sh[255];
}

__global__ void k_scan2(int* __restrict__ bsum, int NB) {
  __shared__ int sh[512];
  int tid = threadIdx.x;
  int v = (tid < NB) ? bsum[tid] : 0;
  sh[tid] = v;
  __syncthreads();
  for (int o = 1; o < 512; o <<= 1) {
    int x = (tid >= o) ? sh[tid - o] : 0;
    __syncthreads();
    sh[tid] += x;
    __syncthreads();
  }
  if (tid < NB) bsum[tid] = sh[tid] - v;
}

__global__ void k_scan3(int* __restrict__ rp, const int* __restrict__ bsum, int N, int E) {
  int i = blockIdx.x * 256 + threadIdx.x;
  if (i < N) rp[i] += bsum[blockIdx.x];
  if (i == 0) rp[N] = E;
}

__global__ void k_scatter(const int* __restrict__ src, const int* __restrict__ dst,
                          const int* __restrict__ rp, int* __restrict__ fill,
                          int* __restrict__ csr, int E) {
  int e = blockIdx.x * blockDim.x + threadIdx.x;
  if (e < E) {
    int d2 = dst[e];
    int pos = rp[d2] + atomicAdd(&fill[d2], 1);
    csr[pos] = src[e];
  }
}

// ---------------- aggregation v2: 4 edges in flight per wave ----------------
// out[n] = t(X[n]) + sum_{e: dst=n} t(X[src]); t = TR ? relu(x*scale+shift) : x
template <int TR>
__global__ __launch_bounds__(256)
void k_agg2(const u16* __restrict__ X, const int* __restrict__ rp,
            const int* __restrict__ csr, const float* __restrict__ scale,
            const float* __restrict__ shift,
            u16* __restrict__ out, int N) {
  int node = blockIdx.x * 4 + (threadIdx.x >> 6);
  if (node >= N) return;
  const int lane = threadIdx.x & 63;
  const int g = lane >> 4;    // edge-slot 0..3
  const int li = lane & 15;   // 16B chunk within row
  const int cb = li * 8;      // col base (8 bf16 per lane)

  float s[8], h[8];
  if constexpr (TR) {
#pragma unroll
    for (int j = 0; j < 8; j += 4) {
      *(float4*)&s[j] = *(const float4*)(scale + cb + j);
      *(float4*)&h[j] = *(const float4*)(shift + cb + j);
    }
  }
  float acc[8];
#pragma unroll
  for (int j = 0; j < 8; ++j) acc[j] = 0.f;

  const int b = rp[node];
  const int cnt = rp[node + 1] - b + 1;  // +1: item 0 = self row
  for (int it = g; it < cnt; it += 4) {
    int sidx = it ? csr[b + it - 1] : node;
    const uint4 v = *(const uint4*)(X + (size_t)sidx * D + cb);
    u32 w[4] = {v.x, v.y, v.z, v.w};
#pragma unroll
    for (int j = 0; j < 4; ++j) {
      float f0 = bf2f(w[j] & 0xFFFFu);
      float f1 = bf2f(w[j] >> 16);
      if constexpr (TR) {
        f0 = fmaxf(f0 * s[2 * j] + h[2 * j], 0.f);
        f1 = fmaxf(f1 * s[2 * j + 1] + h[2 * j + 1], 0.f);
      }
      acc[2 * j] += f0;
      acc[2 * j + 1] += f1;
    }
  }
  // combine the 4 edge-slots (butterfly over lane bits 4,5)
#pragma unroll
  for (int j = 0; j < 8; ++j) {
    acc[j] += __shfl_xor(acc[j], 16, 64);
    acc[j] += __shfl_xor(acc[j], 32, 64);
  }
  if (g == 0) {
    uint4 o;
    o.x = pack2(acc[0], acc[1]);
    o.y = pack2(acc[2], acc[3]);
    o.z = pack2(acc[4], acc[5]);
    o.w = pack2(acc[6], acc[7]);
    *(uint4*)(out + (size_t)node * D + cb) = o;
  }
}

// ---------------- fused GEMM: C = t(A) @ W^T + bias; BN stats via block atomics ----------------
// MODE 0: A bf16, global_load_lds direct
// MODE 1: A bf16, relu(A*scale+shift) on load (reg-staged)
// MODE 2: A fp32, convert on load (reg-staged)
template <int MODE>
__global__ __launch_bounds__(256, 4)
void k_gemm2(const u16* __restrict__ A, const u16* __restrict__ W,
             const float* __restrict__ bias, const float* __restrict__ scale,
             const float* __restrict__ shift,
             u16* __restrict__ Cc, float* __restrict__ stats, int do_stats, int N) {
  __shared__ u16 ls[128 * 128];      // phase1: A half [0,16K) + W half [16K,32K); phase2: C
  __shared__ float swave[4][256];
  u16* lsA = ls;
  u16* lsW = ls + 64 * 128;

  const int t = threadIdx.x;
  const int wv = t >> 6;
  const int lane = t & 63;
  const int rowBase = blockIdx.x * 128;
  const int lrow = lane & 15;
  const int lkb = (lane >> 4) << 4;  // fragment byte offset within 128B k-row

  f32x4 acc[2][8];
#pragma unroll
  for (int m = 0; m < 2; ++m)
#pragma unroll
    for (int n = 0; n < 8; ++n)
      acc[m][n] = (f32x4){0.f, 0.f, 0.f, 0.f};

#pragma unroll
  for (int h = 0; h < 2; ++h) {
    if (h) __syncthreads();  // all fragment reads of half 0 done before overwrite

    // ---- stage A half + W half ----
#pragma unroll
    for (int i = 0; i < 4; ++i) {
      int r0 = wv * 32 + i * 8;          // wave-uniform
      int r = r0 + (lane >> 3);          // 0..127
      int ch = lane & 7;                 // 16B chunk within 128B row
      int sxcol = (ch << 4) ^ ((r & 7) << 4);  // pre-swizzled source column
      // W: always async direct
      gload16((const char*)W + (size_t)r * 256 + h * 128 + sxcol,
              (char*)lsW + r0 * 128);
      if constexpr (MODE == 0) {
        int gr = rowBase + r;
        if (gr >= N) gr = N - 1;  // clamp (dup row; stores/stats guarded later)
        gload16((const char*)A + (size_t)gr * 256 + h * 128 + sxcol,
                (char*)lsA + r0 * 128);
      } else if constexpr (MODE == 1) {
        int gr = rowBase + r;
        uint4 v = make_uint4(0, 0, 0, 0);
        if (gr < N) v = *(const uint4*)(A + (size_t)gr * D + h * 64 + ch * 8);
        u32 vv[4] = {v.x, v.y, v.z, v.w};
        int kb = h * 64 + ch * 8;
#pragma unroll
        for (int j = 0; j < 4; ++j) {
          int k2 = kb + j * 2;
          float f0 = fmaxf(bf2f(vv[j] & 0xFFFFu) * scale[k2] + shift[k2], 0.f);
          float f1 = fmaxf(bf2f(vv[j] >> 16) * scale[k2 + 1] + shift[k2 + 1], 0.f);
          vv[j] = pack2(f0, f1);
        }
        u32 sz = (u32)ASWZ(r, r * 128 + ch * 16);
        *(uint4*)((char*)lsA + sz) = make_uint4(vv[0], vv[1], vv[2], vv[3]);
      } else {
        const float* Af = (const float*)A;
        int gr = rowBase + r;
        float4 v0 = make_float4(0.f, 0.f, 0.f, 0.f), v1 = v0;
        if (gr < N) {
          v0 = *(const float4*)(Af + (size_t)gr * D + h * 64 + ch * 8);
          v1 = *(const float4*)(Af + (size_t)gr * D + h * 64 + ch * 8 + 4);
        }
        u32 vv[4] = {pack2(v0.x, v0.y), pack2(v0.z, v0.w),
                     pack2(v1.x, v1.y), pack2(v1.z, v1.w)};
        u32 sz = (u32)ASWZ(r, r * 128 + ch * 16);
        *(uint4*)((char*)lsA + sz) = make_uint4(vv[0], vv[1], vv[2], vv[3]);
      }
    }
    __syncthreads();  // compiler drains vmcnt/lgkmcnt before s_barrier

    // ---- compute: K-half = 2 x K32 MFMA steps ----
#pragma unroll
    for (int kk2 = 0; kk2 < 2; ++kk2) {
      const int cb = kk2 * 64 + lkb;
      short8 af[2];
#pragma unroll
      for (int m = 0; m < 2; ++m) {
        int r = wv * 32 + m * 16 + lrow;
        af[m] = *(const short8*)((const char*)lsA + ASWZ(r, r * 128 + cb));
      }
#pragma unroll
      for (int n = 0; n < 8; ++n) {
        int rw = n * 16 + lrow;
        short8 bw = *(const short8*)((const char*)lsW + ASWZ(rw, rw * 128 + cb));
#pragma unroll
        for (int m = 0; m < 2; ++m)
          acc[m][n] = __builtin_amdgcn_mfma_f32_16x16x32_bf16(af[m], bw, acc[m][n], 0, 0, 0);
      }
    }
  }

  // ---- epilogue: restage C in LDS (reuse ls), block-local BN partials ----
  __syncthreads();  // all fragment reads done before ls is overwritten with C

  const int rgrp = (lane >> 4) << 2;
  float sacc[8], qacc[8];
#pragma unroll
  for (int n = 0; n < 8; ++n) { sacc[n] = 0.f; qacc[n] = 0.f; }

#pragma unroll
  for (int m = 0; m < 2; ++m) {
    int rl = wv * 32 + m * 16 + rgrp;
#pragma unroll
    for (int n = 0; n < 8; ++n) {
      int col = n * 16 + lrow;
      float bb = bias[col];
      f32x4 a = acc[m][n];
#pragma unroll
      for (int r = 0; r < 4; ++r) {
        int row = rl + r;
        float vv = a[r] + bb;
        *(u16*)((char*)ls + CSWZ(row, row * 256 + col * 2)) = f2bf(vv);
        if (rowBase + row < N) { sacc[n] += vv; qacc[n] += vv * vv; }
      }
    }
  }
  if (do_stats) {
#pragma unroll
    for (int n = 0; n < 8; ++n) {
      float s = sacc[n], q = qacc[n];
      s += __shfl_xor(s, 16, 64); q += __shfl_xor(q, 16, 64);
      s += __shfl_xor(s, 32, 64); q += __shfl_xor(q, 32, 64);
      if (lane < 16) {
        int col = n * 16 + lrow;
        swave[wv][col] = s;
        swave[wv][128 + col] = q;
      }
    }
  }
  __syncthreads();

  // coalesced C copy-out
#pragma unroll
  for (int i = 0; i < 8; ++i) {
    int chunk = i * 256 + t;
    u32 s = (u32)chunk << 4;
    int row = s >> 8;
    if (rowBase + row < N) {
      uint4 v = *(const uint4*)((const char*)ls + CSWZ(row, s));
      *(uint4*)((char*)Cc + (size_t)(rowBase + row) * 256 + (s & 255)) = v;
    }
  }
  if (do_stats) {
    // one atomic per column per block (256 total, coalesced)
    float tot = swave[0][t] + swave[1][t] + swave[2][t] + swave[3][t];
    atomicAdd(&stats[t], tot);
  }
}

// ---------------- BN finalize: stats -> scale/shift, re-zero stats ----------------
__global__ __launch_bounds__(256)
void k_finalize(float* __restrict__ stats, const float* __restrict__ g,
                const float* __restrict__ be, float* __restrict__ scale,
                float* __restrict__ shift, float invN) {
  int t = threadIdx.x;
  float v = stats[t];
  if (t < 128) {
    float sq = stats[128 + t];
    float mean = v * invN;
    float var = sq * invN - mean * mean;
    float rs = rsqrtf(var + 1e-5f);
    float sc = g[t] * rs;
    scale[t] = sc;
    shift[t] = be[t] - mean * sc;
  }
  stats[t] = 0.f;  // ready for next stats GEMM
}

// ---------------- final: out = relu(bn(X))[mask] @ W_out^T + b_out ----------------
#define COUT 10
__global__ __launch_bounds__(256)
void k_out(const u16* __restrict__ X, const int* __restrict__ mask,
           const float* __restrict__ scale, const float* __restrict__ shift,
           const float* __restrict__ Wout, const float* __restrict__ bout,
           float* __restrict__ out, int M) {
  int w = blockIdx.x * 4 + (threadIdx.x >> 6);
  if (w >= M) return;
  int lane = threadIdx.x & 63;
  int c0 = lane * 2;
  int node = mask[w];
  u32 v = *(const u32*)(X + (size_t)node * D + c0);
  float a0 = fmaxf(bf2f(v & 0xFFFFu) * scale[c0] + shift[c0], 0.f);
  float a1 = fmaxf(bf2f(v >> 16) * scale[c0 + 1] + shift[c0 + 1], 0.f);
  float p[COUT];
#pragma unroll
  for (int c = 0; c < COUT; ++c) {
    float2 wv = *(const float2*)(Wout + c * D + c0);
    p[c] = a0 * wv.x + a1 * wv.y;
  }
#pragma unroll
  for (int c = 0; c < COUT; ++c) {
#pragma unroll
    for (int o = 32; o >= 1; o >>= 1)
      p[c] += __shfl_xor(p[c], o, 64);
  }
  if (lane == 0) {
#pragma unroll
    for (int c = 0; c < COUT; ++c)
      out[(size_t)w * COUT + c] = p[c] + bout[c];
  }
}

// ---------------- host ----------------
extern "C" void kernel_launch(void* const* d_in, const int* in_sizes, int n_in,
                              void* d_out, int out_size, void* d_ws, size_t ws_size,
                              hipStream_t stream) {
  const float* x      = (const float*)d_in[0];
  const int*   ei     = (const int*)d_in[1];
  const int*   mask   = (const int*)d_in[2];
  const float* W_init = (const float*)d_in[3];
  const float* b_init = (const float*)d_in[4];
  const float* W1s    = (const float*)d_in[5];
  const float* b1s    = (const float*)d_in[6];
  const float* g1s    = (const float*)d_in[7];
  const float* be1s   = (const float*)d_in[8];
  const float* W2s    = (const float*)d_in[9];
  const float* b2s    = (const float*)d_in[10];
  const float* g2s    = (const float*)d_in[11];
  const float* be2s   = (const float*)d_in[12];
  const float* W_out  = (const float*)d_in[13];
  const float* b_out  = (const float*)d_in[14];

  const int N = in_sizes[0] / D;
  const int E = in_sizes[1] / 2;
  const int M = in_sizes[2];
  const int L = in_sizes[6] / D;

  const int* srcp = ei;
  const int* dstp = ei + E;

  char* ws = (char*)d_ws;
  size_t off = 0;
  auto take = [&](size_t bytes) -> char* {
    off = (off + 255) & ~(size_t)255;
    char* p = ws + off;
    off += bytes;
    return p;
  };
  const int GB = (N + 127) / 128;
  u16* B0    = (u16*)take((size_t)N * D * 2);
  u16* B1    = (u16*)take((size_t)N * D * 2);
  u16* B2    = (u16*)take((size_t)N * D * 2);
  u16* Wb    = (u16*)take((size_t)(1 + 2 * L) * D * D * 2);
  int* csr   = (int*)take((size_t)E * 4);
  int* rp    = (int*)take((size_t)(N + 1) * 4);
  int* cnt   = (int*)take((size_t)N * 4 * 2);
  int* fill  = cnt + N;
  int* bsum  = (int*)take(4096);
  float* stats  = (float*)take(1024);
  float* scaleP = (float*)take(512);
  float* shiftP = (float*)take(512);
  float* scaleQ = (float*)take(512);
  float* shiftQ = (float*)take(512);
  if (off > ws_size) return;

  hipMemsetAsync(cnt, 0, (size_t)N * 8, stream);
  hipMemsetAsync(stats, 0, 1024, stream);

  // weight converts to bf16
  {
    int w4 = D * D / 4;
    k_f2b4<<<(w4 + 255) / 256, 256, 0, stream>>>(W_init, Wb, w4);
    int w4L = L * D * D / 4;
    k_f2b4<<<(w4L + 255) / 256, 256, 0, stream>>>(W1s, Wb + (size_t)D * D, w4L);
    k_f2b4<<<(w4L + 255) / 256, 256, 0, stream>>>(W2s, Wb + (size_t)(1 + L) * D * D, w4L);
  }

  // CSR build
  int NB = (N + 255) / 256;
  k_count<<<(E + 255) / 256, 256, 0, stream>>>(dstp, cnt, E);
  k_scan1<<<NB, 256, 0, stream>>>(cnt, rp, bsum, N);
  k_scan2<<<1, 512, 0, stream>>>(bsum, NB);
  k_scan3<<<NB, 256, 0, stream>>>(rp, bsum, N, E);
  k_scatter<<<(E + 255) / 256, 256, 0, stream>>>(srcp, dstp, rp, fill, csr, E);

  // init linear: B1 = x @ W_init^T + b_init (fp32 A converted on load)
  k_gemm2<2><<<GB, 256, 0, stream>>>((const u16*)x, Wb, b_init, nullptr, nullptr,
                                     B1, stats, 0, N);

  float invN = 1.0f / (float)N;
  int AGB = (N + 3) / 4;

  for (int l = 0; l < L; ++l) {
    if (l == 0)
      k_agg2<0><<<AGB, 256, 0, stream>>>(B1, rp, csr, nullptr, nullptr, B2, N);
    else
      k_agg2<1><<<AGB, 256, 0, stream>>>(B1, rp, csr, scaleQ, shiftQ, B2, N);
    k_gemm2<0><<<GB, 256, 0, stream>>>(B2, Wb + (size_t)(1 + l) * D * D, b1s + l * D,
                                       nullptr, nullptr, B0, stats, 1, N);
    k_finalize<<<1, 256, 0, stream>>>(stats, g1s + l * D, be1s + l * D,
                                      scaleP, shiftP, invN);
    k_gemm2<1><<<GB, 256, 0, stream>>>(B0, Wb + (size_t)(1 + L + l) * D * D, b2s + l * D,
                                       scaleP, shiftP, B1, stats, 1, N);
    k_finalize<<<1, 256, 0, stream>>>(stats, g2s + l * D, be2s + l * D,
                                      scaleQ, shiftQ, invN);
  }

  k_out<<<(M + 3) / 4, 256, 0, stream>>>(B1, mask, scaleQ, shiftQ, W_out, b_out,
                                         (float*)d_out, M);
}